// Round 3
// baseline (5264.914 us; speedup 1.0000x reference)
//
#include <hip/hip_runtime.h>
#include <hip/hip_bf16.h>
#include <math.h>

#define B_    64
#define C_    3
#define HW_   224
#define L_    8
#define D_    384
#define NH_   6
#define DH_   64
#define MLPD_ 1536
#define OUT_  1000
#define S_    197
#define IND_  768
#define BS_   (B_*S_)           // 12608
#define BSD_  ((size_t)BS_*D_)  // 4,841,472 elements

typedef short short8 __attribute__((ext_vector_type(8)));
typedef float f32x4 __attribute__((ext_vector_type(4)));
typedef unsigned short u16;
typedef unsigned int u32;

__device__ inline float gelu_f(float v){ return 0.5f*v*(1.f + erff(v*0.70710678118654752f)); }

// RNE float -> bf16 bits
__device__ inline u16 f2bf(float f){
    u32 u = __float_as_uint(f);
    u32 r = u + 0x7fffu + ((u >> 16) & 1u);
    return (u16)(r >> 16);
}

// ---------------- cls token + pos[0] ----------------
__global__ __launch_bounds__(256)
void vit_cls(const float* __restrict__ cls, const float* __restrict__ pos, float* __restrict__ x){
    int id = blockIdx.x*256 + threadIdx.x;      // 64*384 total
    int b = id / D_, d = id % D_;
    x[(size_t)b*S_*D_ + d] = cls[d] + pos[d];
}

// ---------------- weight transpose + f32->bf16:  W[L][Kd][Nd] -> Bt[L][Nd][Kd] ----------------
__global__ __launch_bounds__(256)
void wt_cvt(const float* __restrict__ W, u16* __restrict__ Bt, int Kd, int Nd){
    __shared__ float t[32][33];
    const int n0 = blockIdx.x*32, k0 = blockIdx.y*32;
    const float* Wl = W + (size_t)blockIdx.z*Kd*Nd;
    u16* Btl = Bt + (size_t)blockIdx.z*Kd*Nd;
    const int tx = threadIdx.x, ty = threadIdx.y;   // block (32,8)
    #pragma unroll
    for (int i=0;i<4;i++){
        int k = ty + i*8;
        t[k][tx] = Wl[(size_t)(k0+k)*Nd + n0 + tx];
    }
    __syncthreads();
    #pragma unroll
    for (int i=0;i<4;i++){
        int n = ty + i*8;
        Btl[(size_t)(n0+n)*Kd + k0 + tx] = f2bf(t[tx][n]);
    }
}

// ---------------- patch embed: gathered A [12544,768] @ W_map[768,384] (f32) ----------------
__global__ __launch_bounds__(256)
void vit_patch(const float* __restrict__ img, const float* __restrict__ Wmap,
               const float* __restrict__ bmap, const float* __restrict__ pos,
               float* __restrict__ x){
    __shared__ float As[16][132];
    __shared__ float Bs[16][132];
    const int tid = threadIdx.x;
    const int tx = tid & 15, ty = tid >> 4;
    const int row0 = blockIdx.x * 128, col0 = blockIdx.y * 128;
    const int am = tid >> 1;           // 0..127
    const int ak = (tid & 1) * 8;      // 0/8
    const int bk = tid >> 4, bn = (tid & 15) * 8;

    const int gm = row0 + am;
    const int ib = gm / 196, p = gm % 196;
    const int py = p / 14, px = p % 14;
    const float* imgb = img + (size_t)ib*C_*HW_*HW_ + (size_t)(py*16)*HW_ + px*16;

    float acc[8][8];
    #pragma unroll
    for (int i=0;i<8;i++)
        #pragma unroll
        for (int j=0;j<8;j++) acc[i][j]=0.f;

    for (int k0 = 0; k0 < IND_; k0 += 16){
        int gk = k0 + ak;
        int c = gk >> 8, rem = gk & 255, ph = rem >> 4, pw = rem & 15;
        const float* ap = imgb + ((size_t)c*HW_ + ph)*HW_ + pw;
        float4 a0 = *(const float4*)ap;
        float4 a1 = *(const float4*)(ap + 4);
        const float* bp = Wmap + (size_t)(k0 + bk)*D_ + col0 + bn;
        float4 b0 = *(const float4*)bp;
        float4 b1 = *(const float4*)(bp + 4);
        __syncthreads();
        As[ak+0][am]=a0.x; As[ak+1][am]=a0.y; As[ak+2][am]=a0.z; As[ak+3][am]=a0.w;
        As[ak+4][am]=a1.x; As[ak+5][am]=a1.y; As[ak+6][am]=a1.z; As[ak+7][am]=a1.w;
        *(float4*)&Bs[bk][bn]   = b0;
        *(float4*)&Bs[bk][bn+4] = b1;
        __syncthreads();
        #pragma unroll
        for (int kk=0;kk<16;kk++){
            float4 av0 = *(const float4*)&As[kk][ty*8];
            float4 av1 = *(const float4*)&As[kk][ty*8+4];
            float4 bv0 = *(const float4*)&Bs[kk][tx*8];
            float4 bv1 = *(const float4*)&Bs[kk][tx*8+4];
            float a[8] = {av0.x,av0.y,av0.z,av0.w,av1.x,av1.y,av1.z,av1.w};
            float b[8] = {bv0.x,bv0.y,bv0.z,bv0.w,bv1.x,bv1.y,bv1.z,bv1.w};
            #pragma unroll
            for (int i=0;i<8;i++)
                #pragma unroll
                for (int j=0;j<8;j++)
                    acc[i][j] = fmaf(a[i], b[j], acc[i][j]);
        }
    }
    #pragma unroll
    for (int i=0;i<8;i++){
        int r = row0 + ty*8 + i;
        int ib2 = r / 196, p2 = r % 196;
        size_t xb = ((size_t)(ib2*S_ + 1 + p2))*D_;
        const float* posr = pos + (size_t)(1+p2)*D_;
        #pragma unroll
        for (int jj=0;jj<8;jj+=4){
            int cc = col0 + tx*8 + jj;
            float4 bi = *(const float4*)(bmap + cc);
            float4 pe = *(const float4*)(posr + cc);
            float4 v;
            v.x = acc[i][jj+0] + bi.x + pe.x;
            v.y = acc[i][jj+1] + bi.y + pe.y;
            v.z = acc[i][jj+2] + bi.z + pe.z;
            v.w = acc[i][jj+3] + bi.w + pe.w;
            *(float4*)(x + xb + cc) = v;
        }
    }
}

// ---------------- layernorm: wave per row; BF=1 writes bf16 ----------------
template<int BF>
__global__ __launch_bounds__(256)
void vit_ln(const float* __restrict__ x, const float* __restrict__ g, const float* __restrict__ bb,
            void* __restrict__ hout){
    const int wave = threadIdx.x >> 6, lane = threadIdx.x & 63;
    const int row = blockIdx.x*4 + wave;
    const float* xp = x + (size_t)row*D_;
    float vals[6];
    #pragma unroll
    for (int i=0;i<6;i++) vals[i] = xp[i*64 + lane];
    float sum = 0.f;
    #pragma unroll
    for (int i=0;i<6;i++) sum += vals[i];
    #pragma unroll
    for (int off=32; off>0; off>>=1) sum += __shfl_xor(sum, off, 64);
    float mean = sum * (1.f/384.f);
    float vs = 0.f;
    #pragma unroll
    for (int i=0;i<6;i++){ float d = vals[i]-mean; vs = fmaf(d,d,vs); }
    #pragma unroll
    for (int off=32; off>0; off>>=1) vs += __shfl_xor(vs, off, 64);
    float rstd = rsqrtf(vs*(1.f/384.f) + 1e-5f);
    #pragma unroll
    for (int i=0;i<6;i++){
        float v = g[i*64+lane]*(vals[i]-mean)*rstd + bb[i*64+lane];
        if (BF) ((u16*)hout)[(size_t)row*D_ + i*64+lane] = f2bf(v);
        else    ((float*)hout)[(size_t)row*D_ + i*64+lane] = v;
    }
}

// ---------------- QKV: per (tokblk, proj*head) 64x64x64 GEMM (f32) ----------------
__global__ __launch_bounds__(256)
void vit_qkv(const float* __restrict__ h,
             const float* __restrict__ Wq, const float* __restrict__ Wk, const float* __restrict__ Wv,
             const float* __restrict__ bq, const float* __restrict__ bk, const float* __restrict__ bv,
             float* __restrict__ q, float* __restrict__ k, float* __restrict__ v){
    __shared__ float As[64][68];
    __shared__ float Bs[64][68];
    const int tid = threadIdx.x;
    const int cb = blockIdx.y;
    const int proj = cb / 6, head = cb % 6;
    const float* W    = proj==0 ? Wq : (proj==1 ? Wk : Wv);
    const float* bias = proj==0 ? bq : (proj==1 ? bk : bv);
    float* outp       = proj==0 ? q  : (proj==1 ? k  : v);
    const int tok0 = blockIdx.x * 64;
    const int m = tid >> 2, k0 = (tid & 3) * 16;
    {
        const float* ap = h + (size_t)(tok0 + m)*D_ + head*64 + k0;
        float f[16];
        #pragma unroll
        for (int j=0;j<4;j++) *(float4*)&f[j*4] = *(const float4*)(ap + j*4);
        #pragma unroll
        for (int j=0;j<16;j++) As[k0+j][m] = f[j];
        const float* wp = W + ((size_t)(head*64 + m))*64 + k0;
        #pragma unroll
        for (int j=0;j<4;j++) *(float4*)&Bs[m][k0 + j*4] = *(const float4*)(wp + j*4);
    }
    __syncthreads();
    const int tx = tid & 15, ty = tid >> 4;
    float acc[4][4];
    #pragma unroll
    for (int i=0;i<4;i++)
        #pragma unroll
        for (int j=0;j<4;j++) acc[i][j]=0.f;
    #pragma unroll 4
    for (int kk=0;kk<64;kk++){
        float4 a = *(const float4*)&As[kk][ty*4];
        float4 b = *(const float4*)&Bs[kk][tx*4];
        float av[4] = {a.x,a.y,a.z,a.w}, bv4[4] = {b.x,b.y,b.z,b.w};
        #pragma unroll
        for (int i=0;i<4;i++)
            #pragma unroll
            for (int j=0;j<4;j++) acc[i][j] = fmaf(av[i], bv4[j], acc[i][j]);
    }
    float4 bi = *(const float4*)(bias + head*64 + tx*4);
    #pragma unroll
    for (int i=0;i<4;i++){
        int tok = tok0 + ty*4 + i;
        int b = tok / S_, s = tok % S_;
        float4 vv;
        vv.x = acc[i][0] + bi.x; vv.y = acc[i][1] + bi.y;
        vv.z = acc[i][2] + bi.z; vv.w = acc[i][3] + bi.w;
        *(float4*)(outp + ((size_t)(b*NH_ + head)*S_ + s)*64 + tx*4) = vv;
    }
}

// ---------------- attention: block per (b,head) (f32) ----------------
__global__ __launch_bounds__(256)
void vit_attn(const float* __restrict__ q, const float* __restrict__ k, const float* __restrict__ v,
              float* __restrict__ x){
    __shared__ float kT[64][204];
    __shared__ float vT[64][204];
    __shared__ float sc[4][4][200];
    __shared__ float qlds[4][4][64];
    const int bh = blockIdx.x;
    const int b = bh / NH_, head = bh % NH_;
    const int tid = threadIdx.x, wave = tid >> 6, lane = tid & 63;
    const size_t base = (size_t)bh * S_ * 64;
    for (int idx = tid; idx < S_*64; idx += 256){
        int s = idx >> 6, d = idx & 63;
        kT[d][s] = k[base + idx];
        vT[d][s] = v[base + idx];
    }
    for (int idx = tid; idx < 64*3; idx += 256){
        int d = idx / 3;
        vT[d][197 + idx%3] = 0.f;
    }
    if (tid < 16){
        sc[tid>>2][tid&3][197] = 0.f;
        sc[tid>>2][tid&3][198] = 0.f;
        sc[tid>>2][tid&3][199] = 0.f;
    }
    __syncthreads();

    for (int rb = wave*4; rb < S_; rb += 16){
        int nrows = S_ - rb; if (nrows > 4) nrows = 4;
        #pragma unroll
        for (int i=0;i<4;i++){
            float qv = (i < nrows) ? q[base + (size_t)(rb+i)*64 + lane] * 0.125f : 0.f;
            qlds[wave][i][lane] = qv;
        }
        float A0[4]={0,0,0,0}, A1[4]={0,0,0,0}, A2[4]={0,0,0,0}, A3[4]={0,0,0,0};
        for (int d=0; d<64; d++){
            float k0v = kT[d][lane];
            float k1v = kT[d][lane+64];
            float k2v = kT[d][lane+128];
            float k3v = (lane < 5) ? kT[d][lane+192] : 0.f;
            #pragma unroll
            for (int i=0;i<4;i++){
                float qd = qlds[wave][i][d];
                A0[i] = fmaf(qd, k0v, A0[i]);
                A1[i] = fmaf(qd, k1v, A1[i]);
                A2[i] = fmaf(qd, k2v, A2[i]);
                A3[i] = fmaf(qd, k3v, A3[i]);
            }
        }
        #pragma unroll
        for (int i=0;i<4;i++){
            if (i < nrows){
                float mx = fmaxf(fmaxf(A0[i], A1[i]), A2[i]);
                if (lane < 5) mx = fmaxf(mx, A3[i]);
                #pragma unroll
                for (int off=32; off>0; off>>=1) mx = fmaxf(mx, __shfl_xor(mx, off, 64));
                float e0 = expf(A0[i]-mx), e1 = expf(A1[i]-mx), e2 = expf(A2[i]-mx);
                float e3 = (lane < 5) ? expf(A3[i]-mx) : 0.f;
                float ss = e0+e1+e2+e3;
                #pragma unroll
                for (int off=32; off>0; off>>=1) ss += __shfl_xor(ss, off, 64);
                float inv = 1.f / ss;
                sc[wave][i][lane]     = e0*inv;
                sc[wave][i][lane+64]  = e1*inv;
                sc[wave][i][lane+128] = e2*inv;
                if (lane < 5) sc[wave][i][lane+192] = e3*inv;
            }
        }
        float o[4] = {0,0,0,0};
        for (int k4=0; k4<200; k4+=4){
            float4 vv = *(const float4*)&vT[lane][k4];
            #pragma unroll
            for (int i=0;i<4;i++){
                float4 pp = *(const float4*)&sc[wave][i][k4];
                o[i] = fmaf(vv.x, pp.x, o[i]);
                o[i] = fmaf(vv.y, pp.y, o[i]);
                o[i] = fmaf(vv.z, pp.z, o[i]);
                o[i] = fmaf(vv.w, pp.w, o[i]);
            }
        }
        for (int i=0;i<nrows;i++){
            size_t xi = ((size_t)(b*S_ + rb + i))*D_ + head*64 + lane;
            x[xi] += o[i];
        }
    }
}

// ---------------- bf16 MFMA GEMM 128x128xBK32, 4 waves, 64x64/wave ----------------
// A: ABF16 ? bf16[M][K] : f32[M][K] (converted during staging). Bt: bf16 [N][K].
// EPI 0: out = gelu(acc+bias) (f32). EPI 1: out += acc+bias (residual).
template<int ABF16, int EPI>
__global__ __launch_bounds__(256)
void vit_gemm_mfma(const void* __restrict__ Aptr, const u16* __restrict__ Bt,
                   const float* __restrict__ bias, float* __restrict__ outp,
                   int M, int N, int K){
    __shared__ u16 As[128][40];   // 80B row stride: 16B-aligned, ~2-way banks
    __shared__ u16 Bs[128][40];   // Bs[n][k]
    const int tid = threadIdx.x;
    const int lane = tid & 63, w = tid >> 6;
    const int wr = w >> 1, wc = w & 1;
    const int lr = lane >> 4, lc = lane & 15;
    const int row0 = blockIdx.x * 128, col0 = blockIdx.y * 128;

    f32x4 acc[4][4];
    #pragma unroll
    for (int i=0;i<4;i++)
        #pragma unroll
        for (int j=0;j<4;j++)
            #pragma unroll
            for (int r=0;r<4;r++) acc[i][j][r] = 0.f;

    for (int k0 = 0; k0 < K; k0 += 32){
        uint4 da[2], db[2];
        #pragma unroll
        for (int i=0;i<2;i++){
            const int ch = tid + 256*i;
            const int r = ch >> 2, qq = ch & 3;
            const int gm = row0 + r;
            if (ABF16){
                if (gm < M)
                    da[i] = *(const uint4*)((const u16*)Aptr + (size_t)gm*K + k0 + qq*8);
                else
                    da[i] = make_uint4(0u,0u,0u,0u);
            } else {
                if (gm < M){
                    const float* ap = (const float*)Aptr + (size_t)gm*K + k0 + qq*8;
                    float4 f0 = *(const float4*)ap;
                    float4 f1 = *(const float4*)(ap+4);
                    da[i] = make_uint4((u32)f2bf(f0.x) | ((u32)f2bf(f0.y)<<16),
                                       (u32)f2bf(f0.z) | ((u32)f2bf(f0.w)<<16),
                                       (u32)f2bf(f1.x) | ((u32)f2bf(f1.y)<<16),
                                       (u32)f2bf(f1.z) | ((u32)f2bf(f1.w)<<16));
                } else da[i] = make_uint4(0u,0u,0u,0u);
            }
            db[i] = *(const uint4*)(Bt + (size_t)(col0 + r)*K + k0 + qq*8);
        }
        __syncthreads();
        #pragma unroll
        for (int i=0;i<2;i++){
            const int ch = tid + 256*i;
            const int r = ch >> 2, qq = ch & 3;
            *(uint4*)&As[r][qq*8] = da[i];
            *(uint4*)&Bs[r][qq*8] = db[i];
        }
        __syncthreads();
        short8 af[4], bf[4];
        #pragma unroll
        for (int i=0;i<4;i++) af[i] = *(const short8*)&As[wr*64 + i*16 + lc][lr*8];
        #pragma unroll
        for (int j=0;j<4;j++) bf[j] = *(const short8*)&Bs[wc*64 + j*16 + lc][lr*8];
        #pragma unroll
        for (int i=0;i<4;i++)
            #pragma unroll
            for (int j=0;j<4;j++)
                acc[i][j] = __builtin_amdgcn_mfma_f32_16x16x32_bf16(af[i], bf[j], acc[i][j], 0, 0, 0);
    }

    const int rbase = row0 + wr*64;
    const int cbase = col0 + wc*64;
    #pragma unroll
    for (int i=0;i<4;i++)
        #pragma unroll
        for (int r=0;r<4;r++){
            int row = rbase + i*16 + lr*4 + r;
            if (row < M){
                float* orow = outp + (size_t)row*N;
                #pragma unroll
                for (int j=0;j<4;j++){
                    int col = cbase + j*16 + lc;
                    float v = acc[i][j][r] + bias[col];
                    if (EPI == 0) orow[col] = gelu_f(v);
                    else          orow[col] += v;
                }
            }
        }
}

// ---------------- head: logits + softmax, block per image ----------------
__global__ __launch_bounds__(256)
void vit_head(const float* __restrict__ x, const float* __restrict__ Wh,
              const float* __restrict__ bh, float* __restrict__ out){
    __shared__ float xrow[D_];
    __shared__ float red[8];
    const int b = blockIdx.x, t = threadIdx.x;
    for (int i=t; i<D_; i+=256) xrow[i] = x[(size_t)b*S_*D_ + i];
    __syncthreads();
    float acc[4] = {0,0,0,0};
    for (int d=0; d<D_; d++){
        float xv = xrow[d];
        const float* wp = Wh + (size_t)d*OUT_ + t;
        #pragma unroll
        for (int j=0;j<4;j++){
            int c = t + j*256;
            if (c < OUT_) acc[j] = fmaf(xv, wp[j*256], acc[j]);
        }
    }
    #pragma unroll
    for (int j=0;j<4;j++){ int c = t + j*256; if (c < OUT_) acc[j] += bh[c]; }
    float mx = -1e30f;
    #pragma unroll
    for (int j=0;j<4;j++){ int c = t + j*256; if (c < OUT_) mx = fmaxf(mx, acc[j]); }
    #pragma unroll
    for (int off=32; off>0; off>>=1) mx = fmaxf(mx, __shfl_xor(mx, off, 64));
    if ((t & 63) == 0) red[t>>6] = mx;
    __syncthreads();
    mx = fmaxf(fmaxf(red[0],red[1]), fmaxf(red[2],red[3]));
    float e[4]; float ss = 0.f;
    #pragma unroll
    for (int j=0;j<4;j++){
        int c = t + j*256;
        if (c < OUT_){ e[j] = expf(acc[j]-mx); ss += e[j]; } else e[j] = 0.f;
    }
    #pragma unroll
    for (int off=32; off>0; off>>=1) ss += __shfl_xor(ss, off, 64);
    if ((t & 63) == 0) red[4 + (t>>6)] = ss;
    __syncthreads();
    ss = red[4]+red[5]+red[6]+red[7];
    float inv = 1.f/ss;
    #pragma unroll
    for (int j=0;j<4;j++){
        int c = t + j*256;
        if (c < OUT_) out[(size_t)b*OUT_ + c] = e[j]*inv;
    }
}

extern "C" void kernel_launch(void* const* d_in, const int* in_sizes, int n_in,
                              void* d_out, int out_size, void* d_ws, size_t ws_size,
                              hipStream_t stream){
    const float* images = (const float*)d_in[0];
    const float* W_map  = (const float*)d_in[1];
    const float* b_map  = (const float*)d_in[2];
    const float* cls    = (const float*)d_in[3];
    const float* pos    = (const float*)d_in[4];
    const float* ln1s   = (const float*)d_in[5];
    const float* ln1b   = (const float*)d_in[6];
    const float* Wq     = (const float*)d_in[7];
    const float* bq     = (const float*)d_in[8];
    const float* Wk     = (const float*)d_in[9];
    const float* bk     = (const float*)d_in[10];
    const float* Wv     = (const float*)d_in[11];
    const float* bv     = (const float*)d_in[12];
    const float* ln2s   = (const float*)d_in[13];
    const float* ln2b   = (const float*)d_in[14];
    const float* W1     = (const float*)d_in[15];
    const float* b1     = (const float*)d_in[16];
    const float* W2     = (const float*)d_in[17];
    const float* b2     = (const float*)d_in[18];
    const float* Wh     = (const float*)d_in[19];
    const float* bh     = (const float*)d_in[20];
    float* out = (float*)d_out;

    // workspace layout (floats):
    // [x: BSD_][ h/q/k/v : 4*BSD_  <-- reused as m (BS_*1536 = 4*BSD_) after attn ]
    // [hbf: BSD_ u16 = BSD_/2 floats][wt1: 8*384*1536 u16][wt2: same]
    float* ws = (float*)d_ws;
    float*  x   = ws;
    float*  h   = ws + BSD_;
    float*  qb  = ws + 2*BSD_;
    float*  kb  = ws + 3*BSD_;
    float*  vb  = ws + 4*BSD_;
    float*  m   = ws + BSD_;                 // overlaps h,qb,kb,vb (dead by MLP time)
    u16*    hbf = (u16*)(ws + 5*BSD_);       // BSD_ u16
    u16*    wt1 = hbf + BSD_;                // 8*D_*MLPD_ u16
    u16*    wt2 = wt1 + (size_t)L_*D_*MLPD_; // 8*MLPD_*D_ u16

    // weights -> bf16 transposed [N][K], all layers
    wt_cvt<<<dim3(MLPD_/32, D_/32, L_), dim3(32,8), 0, stream>>>(W1, wt1, D_, MLPD_);
    wt_cvt<<<dim3(D_/32, MLPD_/32, L_), dim3(32,8), 0, stream>>>(W2, wt2, MLPD_, D_);

    vit_cls<<<dim3(96), dim3(256), 0, stream>>>(cls, pos, x);
    vit_patch<<<dim3(98,3), dim3(256), 0, stream>>>(images, W_map, b_map, pos, x);

    for (int l=0; l<L_; l++){
        vit_ln<0><<<dim3(BS_/4), dim3(256), 0, stream>>>(x, ln1s + l*D_, ln1b + l*D_, (void*)h);
        vit_qkv<<<dim3(197,18), dim3(256), 0, stream>>>(h,
            Wq + (size_t)l*NH_*DH_*DH_, Wk + (size_t)l*NH_*DH_*DH_, Wv + (size_t)l*NH_*DH_*DH_,
            bq + (size_t)l*NH_*DH_,     bk + (size_t)l*NH_*DH_,     bv + (size_t)l*NH_*DH_,
            qb, kb, vb);
        vit_attn<<<dim3(B_*NH_), dim3(256), 0, stream>>>(qb, kb, vb, x);
        vit_ln<1><<<dim3(BS_/4), dim3(256), 0, stream>>>(x, ln2s + l*D_, ln2b + l*D_, (void*)hbf);
        vit_gemm_mfma<1,0><<<dim3(99,12), dim3(256), 0, stream>>>(
            (const void*)hbf, wt1 + (size_t)l*D_*MLPD_, b1 + (size_t)l*MLPD_, m, BS_, MLPD_, D_);
        vit_gemm_mfma<0,1><<<dim3(99,3), dim3(256), 0, stream>>>(
            (const void*)m, wt2 + (size_t)l*MLPD_*D_, b2 + (size_t)l*D_, x, BS_, D_, MLPD_);
    }
    vit_head<<<dim3(B_), dim3(256), 0, stream>>>(x, Wh, bh, out);
}

// Round 8
// 2472.732 us; speedup vs baseline: 2.1292x; 2.1292x over previous
//
#include <hip/hip_runtime.h>
#include <hip/hip_bf16.h>
#include <math.h>

#define B_    64
#define C_    3
#define HW_   224
#define L_    8
#define D_    384
#define NH_   6
#define DH_   64
#define MLPD_ 1536
#define OUT_  1000
#define S_    197
#define SP_   224               // padded seq for attn buffers
#define IND_  768
#define BS_   (B_*S_)           // 12608
#define BSD_  ((size_t)BS_*D_)  // 4,841,472 elements

typedef short short8 __attribute__((ext_vector_type(8)));
typedef float f32x4 __attribute__((ext_vector_type(4)));
typedef unsigned short u16;
typedef unsigned int u32;

#define KLD 72    // K/Q LDS row stride (u16)
#define PLD 232   // P/VT LDS row stride (u16)

__device__ inline float gelu_f(float v){ return 0.5f*v*(1.f + erff(v*0.70710678118654752f)); }

// RNE float -> bf16 bits
__device__ inline u16 f2bf(float f){
    u32 u = __float_as_uint(f);
    u32 r = u + 0x7fffu + ((u >> 16) & 1u);
    return (u16)(r >> 16);
}

// ---------------- cls token + pos[0] ----------------
__global__ __launch_bounds__(256)
void vit_cls(const float* __restrict__ cls, const float* __restrict__ pos, float* __restrict__ x){
    int id = blockIdx.x*256 + threadIdx.x;
    int b = id / D_, d = id % D_;
    x[(size_t)b*S_*D_ + d] = cls[d] + pos[d];
}

// ---------------- weight transpose + f32->bf16:  W[L][Kd][Nd] -> Bt[L][Nd][Kd] ----------------
__global__ __launch_bounds__(256)
void wt_cvt(const float* __restrict__ W, u16* __restrict__ Bt, int Kd, int Nd){
    __shared__ float t[32][33];
    const int n0 = blockIdx.x*32, k0 = blockIdx.y*32;
    const float* Wl = W + (size_t)blockIdx.z*Kd*Nd;
    u16* Btl = Bt + (size_t)blockIdx.z*Kd*Nd;
    const int tx = threadIdx.x, ty = threadIdx.y;   // block (32,8)
    #pragma unroll
    for (int i=0;i<4;i++){
        int k = ty + i*8;
        t[k][tx] = Wl[(size_t)(k0+k)*Nd + n0 + tx];
    }
    __syncthreads();
    #pragma unroll
    for (int i=0;i<4;i++){
        int n = ty + i*8;
        Btl[(size_t)(n0+n)*Kd + k0 + tx] = f2bf(t[tx][n]);
    }
}

// ---------------- patch embed (f32 VALU) ----------------
__global__ __launch_bounds__(256)
void vit_patch(const float* __restrict__ img, const float* __restrict__ Wmap,
               const float* __restrict__ bmap, const float* __restrict__ pos,
               float* __restrict__ x){
    __shared__ float As[16][132];
    __shared__ float Bs[16][132];
    const int tid = threadIdx.x;
    const int tx = tid & 15, ty = tid >> 4;
    const int row0 = blockIdx.x * 128, col0 = blockIdx.y * 128;
    const int am = tid >> 1;
    const int ak = (tid & 1) * 8;
    const int bk = tid >> 4, bn = (tid & 15) * 8;

    const int gm = row0 + am;
    const int ib = gm / 196, p = gm % 196;
    const int py = p / 14, px = p % 14;
    const float* imgb = img + (size_t)ib*C_*HW_*HW_ + (size_t)(py*16)*HW_ + px*16;

    float acc[8][8];
    #pragma unroll
    for (int i=0;i<8;i++)
        #pragma unroll
        for (int j=0;j<8;j++) acc[i][j]=0.f;

    for (int k0 = 0; k0 < IND_; k0 += 16){
        int gk = k0 + ak;
        int c = gk >> 8, rem = gk & 255, ph = rem >> 4, pw = rem & 15;
        const float* ap = imgb + ((size_t)c*HW_ + ph)*HW_ + pw;
        float4 a0 = *(const float4*)ap;
        float4 a1 = *(const float4*)(ap + 4);
        const float* bp = Wmap + (size_t)(k0 + bk)*D_ + col0 + bn;
        float4 b0 = *(const float4*)bp;
        float4 b1 = *(const float4*)(bp + 4);
        __syncthreads();
        As[ak+0][am]=a0.x; As[ak+1][am]=a0.y; As[ak+2][am]=a0.z; As[ak+3][am]=a0.w;
        As[ak+4][am]=a1.x; As[ak+5][am]=a1.y; As[ak+6][am]=a1.z; As[ak+7][am]=a1.w;
        *(float4*)&Bs[bk][bn]   = b0;
        *(float4*)&Bs[bk][bn+4] = b1;
        __syncthreads();
        #pragma unroll
        for (int kk=0;kk<16;kk++){
            float4 av0 = *(const float4*)&As[kk][ty*8];
            float4 av1 = *(const float4*)&As[kk][ty*8+4];
            float4 bv0 = *(const float4*)&Bs[kk][tx*8];
            float4 bv1 = *(const float4*)&Bs[kk][tx*8+4];
            float a[8] = {av0.x,av0.y,av0.z,av0.w,av1.x,av1.y,av1.z,av1.w};
            float b[8] = {bv0.x,bv0.y,bv0.z,bv0.w,bv1.x,bv1.y,bv1.z,bv1.w};
            #pragma unroll
            for (int i=0;i<8;i++)
                #pragma unroll
                for (int j=0;j<8;j++)
                    acc[i][j] = fmaf(a[i], b[j], acc[i][j]);
        }
    }
    #pragma unroll
    for (int i=0;i<8;i++){
        int r = row0 + ty*8 + i;
        int ib2 = r / 196, p2 = r % 196;
        size_t xb = ((size_t)(ib2*S_ + 1 + p2))*D_;
        const float* posr = pos + (size_t)(1+p2)*D_;
        #pragma unroll
        for (int jj=0;jj<8;jj+=4){
            int cc = col0 + tx*8 + jj;
            float4 bi = *(const float4*)(bmap + cc);
            float4 pe = *(const float4*)(posr + cc);
            float4 v;
            v.x = acc[i][jj+0] + bi.x + pe.x;
            v.y = acc[i][jj+1] + bi.y + pe.y;
            v.z = acc[i][jj+2] + bi.z + pe.z;
            v.w = acc[i][jj+3] + bi.w + pe.w;
            *(float4*)(x + xb + cc) = v;
        }
    }
}

// ---------------- layernorm: wave per row; BF=1 writes bf16 ----------------
template<int BF>
__global__ __launch_bounds__(256)
void vit_ln(const float* __restrict__ x, const float* __restrict__ g, const float* __restrict__ bb,
            void* __restrict__ hout){
    const int wave = threadIdx.x >> 6, lane = threadIdx.x & 63;
    const int row = blockIdx.x*4 + wave;
    const float* xp = x + (size_t)row*D_;
    float vals[6];
    #pragma unroll
    for (int i=0;i<6;i++) vals[i] = xp[i*64 + lane];
    float sum = 0.f;
    #pragma unroll
    for (int i=0;i<6;i++) sum += vals[i];
    #pragma unroll
    for (int off=32; off>0; off>>=1) sum += __shfl_xor(sum, off, 64);
    float mean = sum * (1.f/384.f);
    float vs = 0.f;
    #pragma unroll
    for (int i=0;i<6;i++){ float d = vals[i]-mean; vs = fmaf(d,d,vs); }
    #pragma unroll
    for (int off=32; off>0; off>>=1) vs += __shfl_xor(vs, off, 64);
    float rstd = rsqrtf(vs*(1.f/384.f) + 1e-5f);
    #pragma unroll
    for (int i=0;i<6;i++){
        float v = g[i*64+lane]*(vals[i]-mean)*rstd + bb[i*64+lane];
        if (BF) ((u16*)hout)[(size_t)row*D_ + i*64+lane] = f2bf(v);
        else    ((float*)hout)[(size_t)row*D_ + i*64+lane] = v;
    }
}

// ---------------- QKV: 64x64x64 f32 GEMM, bf16 outputs: q(scaled), k, v^T ----------------
__global__ __launch_bounds__(256)
void vit_qkv(const float* __restrict__ h,
             const float* __restrict__ Wq, const float* __restrict__ Wk, const float* __restrict__ Wv,
             const float* __restrict__ bq, const float* __restrict__ bk, const float* __restrict__ bv,
             u16* __restrict__ q, u16* __restrict__ k, u16* __restrict__ vt){
    __shared__ float As[64][68];
    __shared__ float Bs[64][68];
    const int tid = threadIdx.x;
    const int cb = blockIdx.y;
    const int proj = cb / 6, head = cb % 6;
    const float* W    = proj==0 ? Wq : (proj==1 ? Wk : Wv);
    const float* bias = proj==0 ? bq : (proj==1 ? bk : bv);
    const int tok0 = blockIdx.x * 64;
    const int m = tid >> 2, k0 = (tid & 3) * 16;
    {
        const float* ap = h + (size_t)(tok0 + m)*D_ + head*64 + k0;
        float f[16];
        #pragma unroll
        for (int j=0;j<4;j++) *(float4*)&f[j*4] = *(const float4*)(ap + j*4);
        #pragma unroll
        for (int j=0;j<16;j++) As[k0+j][m] = f[j];
        const float* wp = W + ((size_t)(head*64 + m))*64 + k0;
        #pragma unroll
        for (int j=0;j<4;j++) *(float4*)&Bs[m][k0 + j*4] = *(const float4*)(wp + j*4);
    }
    __syncthreads();
    const int tx = tid & 15, ty = tid >> 4;
    float acc[4][4];
    #pragma unroll
    for (int i=0;i<4;i++)
        #pragma unroll
        for (int j=0;j<4;j++) acc[i][j]=0.f;
    #pragma unroll 4
    for (int kk=0;kk<64;kk++){
        float4 a = *(const float4*)&As[kk][ty*4];
        float4 b = *(const float4*)&Bs[kk][tx*4];
        float av[4] = {a.x,a.y,a.z,a.w}, bv4[4] = {b.x,b.y,b.z,b.w};
        #pragma unroll
        for (int i=0;i<4;i++)
            #pragma unroll
            for (int j=0;j<4;j++) acc[i][j] = fmaf(av[i], bv4[j], acc[i][j]);
    }
    float4 bi = *(const float4*)(bias + head*64 + tx*4);
    const float qs = (proj==0) ? 0.125f : 1.f;
    #pragma unroll
    for (int i=0;i<4;i++){
        int tok = tok0 + ty*4 + i;
        int b = tok / S_, s = tok % S_;
        int bh = b*NH_ + head;
        float v0 = (acc[i][0] + bi.x) * qs;
        float v1 = (acc[i][1] + bi.y) * qs;
        float v2 = (acc[i][2] + bi.z) * qs;
        float v3 = (acc[i][3] + bi.w) * qs;
        if (proj == 2){
            vt[((size_t)bh*64 + tx*4+0)*SP_ + s] = f2bf(v0);
            vt[((size_t)bh*64 + tx*4+1)*SP_ + s] = f2bf(v1);
            vt[((size_t)bh*64 + tx*4+2)*SP_ + s] = f2bf(v2);
            vt[((size_t)bh*64 + tx*4+3)*SP_ + s] = f2bf(v3);
        } else {
            u16* outp = (proj==0 ? q : k) + ((size_t)bh*SP_ + s)*64 + tx*4;
            uint2 pk;
            pk.x = (u32)f2bf(v0) | ((u32)f2bf(v1) << 16);
            pk.y = (u32)f2bf(v2) | ((u32)f2bf(v3) << 16);
            *(uint2*)outp = pk;
        }
    }
}

// ---------------- attention: MFMA flash-style, block per (bh, q-tile of 64) ----------------
__global__ __launch_bounds__(256)
void vit_attn_mfma(const u16* __restrict__ qg, const u16* __restrict__ kg,
                   const u16* __restrict__ vtg, float* __restrict__ x){
    __shared__ u16 KP[224*KLD];   // K [224][72]; reused as P [64][232] after QK^T
    __shared__ u16 VT[64*PLD];    // V^T [64][232]
    __shared__ u16 QS[64*KLD];    // Q tile [64][72]
    const int bh = blockIdx.x;
    const int q0 = blockIdx.y * 64;
    const int b = bh / NH_, head = bh % NH_;
    const int tid = threadIdx.x, lane = tid & 63, w = tid >> 6;
    const int lr = lane >> 4, lc = lane & 15;

    const u16* qhb = qg + (size_t)bh*SP_*64;
    const u16* khb = kg + (size_t)bh*SP_*64;
    const u16* vhb = vtg + (size_t)bh*64*SP_;

    // stage Q (64 rows), K (224 rows), V^T (64x224)
    #pragma unroll
    for (int i=0;i<2;i++){
        int c = tid + 256*i; int r = c>>3, o=(c&7)*8;
        *(uint4*)&QS[r*KLD + o] = *(const uint4*)&qhb[(size_t)(q0 + r)*64 + o];
    }
    #pragma unroll
    for (int i=0;i<7;i++){
        int c = tid + 256*i; int r = c>>3, o=(c&7)*8;
        *(uint4*)&KP[r*KLD + o] = *(const uint4*)&khb[(size_t)r*64 + o];
    }
    {
        int r = tid >> 2, o0 = (tid & 3)*8;
        #pragma unroll
        for (int j=0;j<7;j++){
            int o = o0 + j*32;
            *(uint4*)&VT[r*PLD + o] = *(const uint4*)&vhb[(size_t)r*SP_ + o];
        }
    }
    // Barrier BEFORE zeroing: the staging loop above also writes cols 197..223
    // (from different waves). Without this barrier the staged garbage (stale f32
    // halves, possibly bf16 inf/NaN in layers>=1) can land AFTER the zeroes ->
    // P(=0) * inf = NaN in the PV MFMA. Zero must deterministically win.
    __syncthreads();
    #pragma unroll
    for (int i=0;i<8;i++){
        int idx = tid + 256*i;            // 0..2047
        int r = idx >> 5, cix = idx & 31; // col 197..228 < PLD=232
        VT[r*PLD + S_ + cix] = 0;
    }
    __syncthreads();

    // QK^T: wave w computes q-rows w*16..w*16+15 x all 224 k-cols
    f32x4 sc[14];
    #pragma unroll
    for (int t=0;t<14;t++)
        #pragma unroll
        for (int r=0;r<4;r++) sc[t][r] = 0.f;
    const int arow = (w*16 + lc)*KLD;
    #pragma unroll
    for (int kk=0; kk<64; kk+=32){
        short8 aq = *(const short8*)&QS[arow + kk + lr*8];
        #pragma unroll
        for (int t=0;t<14;t++){
            short8 bk8 = *(const short8*)&KP[(t*16+lc)*KLD + kk + lr*8];
            sc[t] = __builtin_amdgcn_mfma_f32_16x16x32_bf16(aq, bk8, sc[t], 0, 0, 0);
        }
    }
    __syncthreads();   // all waves done reading K; KP can become P

    // softmax (register, 16-lane shuffle reduce); C-row = w*16 + lr*4 + r, col = t*16+lc
    float inv_s[4];
    u16 pb[4][14];
    #pragma unroll
    for (int r=0;r<4;r++){
        float sv[14];
        float mx = -1e30f;
        #pragma unroll
        for (int t=0;t<14;t++){
            float s = sc[t][r];
            if (t*16 + lc >= S_) s = -1e30f;
            sv[t] = s;
            mx = fmaxf(mx, s);
        }
        #pragma unroll
        for (int off=1; off<16; off<<=1) mx = fmaxf(mx, __shfl_xor(mx, off, 64));
        float sum = 0.f;
        #pragma unroll
        for (int t=0;t<14;t++){
            float e = expf(sv[t] - mx);
            sum += e;
            pb[r][t] = f2bf(e);
        }
        #pragma unroll
        for (int off=1; off<16; off<<=1) sum += __shfl_xor(sum, off, 64);
        inv_s[r] = 1.f / sum;
    }
    // write unnormalized P (bf16) into KP region, layout [64][PLD]
    #pragma unroll
    for (int r=0;r<4;r++){
        int prow = (w*16 + lr*4 + r)*PLD;
        #pragma unroll
        for (int t=0;t<14;t++) KP[prow + t*16 + lc] = pb[r][t];
    }
    __syncthreads();

    // PV: out = P[16 x 224] * V -> wave w: q-rows w*16..+15, d-cols 0..63
    f32x4 oc[4];
    #pragma unroll
    for (int j=0;j<4;j++)
        #pragma unroll
        for (int r=0;r<4;r++) oc[j][r] = 0.f;
    const int prow2 = (w*16 + lc)*PLD;
    #pragma unroll
    for (int ks=0; ks<7; ks++){
        short8 ap = *(const short8*)&KP[prow2 + ks*32 + lr*8];
        #pragma unroll
        for (int j=0;j<4;j++){
            short8 vv = *(const short8*)&VT[(j*16+lc)*PLD + ks*32 + lr*8];
            oc[j] = __builtin_amdgcn_mfma_f32_16x16x32_bf16(ap, vv, oc[j], 0, 0, 0);
        }
    }
    // epilogue: x += (P.V) * inv_sum  (residual)
    #pragma unroll
    for (int r=0;r<4;r++){
        int qrow = q0 + w*16 + lr*4 + r;
        if (qrow < S_){
            float* xp = x + ((size_t)b*S_ + qrow)*D_ + head*64;
            float is = inv_s[r];
            #pragma unroll
            for (int j=0;j<4;j++)
                xp[j*16 + lc] += oc[j][r] * is;
        }
    }
}

// ---------------- bf16 MFMA GEMM 128x128xBK32, 4 waves, 64x64/wave ----------------
template<int ABF16, int EPI>
__global__ __launch_bounds__(256)
void vit_gemm_mfma(const void* __restrict__ Aptr, const u16* __restrict__ Bt,
                   const float* __restrict__ bias, float* __restrict__ outp,
                   int M, int N, int K){
    __shared__ u16 As[128][40];
    __shared__ u16 Bs[128][40];
    const int tid = threadIdx.x;
    const int lane = tid & 63, w = tid >> 6;
    const int wr = w >> 1, wc = w & 1;
    const int lr = lane >> 4, lc = lane & 15;
    const int row0 = blockIdx.x * 128, col0 = blockIdx.y * 128;

    f32x4 acc[4][4];
    #pragma unroll
    for (int i=0;i<4;i++)
        #pragma unroll
        for (int j=0;j<4;j++)
            #pragma unroll
            for (int r=0;r<4;r++) acc[i][j][r] = 0.f;

    for (int k0 = 0; k0 < K; k0 += 32){
        uint4 da[2], db[2];
        #pragma unroll
        for (int i=0;i<2;i++){
            const int ch = tid + 256*i;
            const int r = ch >> 2, qq = ch & 3;
            const int gm = row0 + r;
            if (ABF16){
                if (gm < M)
                    da[i] = *(const uint4*)((const u16*)Aptr + (size_t)gm*K + k0 + qq*8);
                else
                    da[i] = make_uint4(0u,0u,0u,0u);
            } else {
                if (gm < M){
                    const float* ap = (const float*)Aptr + (size_t)gm*K + k0 + qq*8;
                    float4 f0 = *(const float4*)ap;
                    float4 f1 = *(const float4*)(ap+4);
                    da[i] = make_uint4((u32)f2bf(f0.x) | ((u32)f2bf(f0.y)<<16),
                                       (u32)f2bf(f0.z) | ((u32)f2bf(f0.w)<<16),
                                       (u32)f2bf(f1.x) | ((u32)f2bf(f1.y)<<16),
                                       (u32)f2bf(f1.z) | ((u32)f2bf(f1.w)<<16));
                } else da[i] = make_uint4(0u,0u,0u,0u);
            }
            db[i] = *(const uint4*)(Bt + (size_t)(col0 + r)*K + k0 + qq*8);
        }
        __syncthreads();
        #pragma unroll
        for (int i=0;i<2;i++){
            const int ch = tid + 256*i;
            const int r = ch >> 2, qq = ch & 3;
            *(uint4*)&As[r][qq*8] = da[i];
            *(uint4*)&Bs[r][qq*8] = db[i];
        }
        __syncthreads();
        short8 af[4], bf[4];
        #pragma unroll
        for (int i=0;i<4;i++) af[i] = *(const short8*)&As[wr*64 + i*16 + lc][lr*8];
        #pragma unroll
        for (int j=0;j<4;j++) bf[j] = *(const short8*)&Bs[wc*64 + j*16 + lc][lr*8];
        #pragma unroll
        for (int i=0;i<4;i++)
            #pragma unroll
            for (int j=0;j<4;j++)
                acc[i][j] = __builtin_amdgcn_mfma_f32_16x16x32_bf16(af[i], bf[j], acc[i][j], 0, 0, 0);
    }

    const int rbase = row0 + wr*64;
    const int cbase = col0 + wc*64;
    #pragma unroll
    for (int i=0;i<4;i++)
        #pragma unroll
        for (int r=0;r<4;r++){
            int row = rbase + i*16 + lr*4 + r;
            if (row < M){
                float* orow = outp + (size_t)row*N;
                #pragma unroll
                for (int j=0;j<4;j++){
                    int col = cbase + j*16 + lc;
                    float v = acc[i][j][r] + bias[col];
                    if (EPI == 0) orow[col] = gelu_f(v);
                    else          orow[col] += v;
                }
            }
        }
}

// ---------------- head: logits (grid 4x64), then softmax (grid 64) ----------------
__global__ __launch_bounds__(256)
void head_logits(const float* __restrict__ x, const float* __restrict__ Wh,
                 const float* __restrict__ bhp, float* __restrict__ logits){
    __shared__ float xs[D_];
    const int b = blockIdx.y, j = blockIdx.x, t = threadIdx.x;
    for (int i=t; i<D_; i+=256) xs[i] = x[(size_t)b*S_*D_ + i];
    __syncthreads();
    if (t < 250){
        const int c = j*250 + t;
        float acc = 0.f;
        for (int d=0; d<D_; d++)
            acc = fmaf(xs[d], Wh[(size_t)d*OUT_ + c], acc);
        logits[(size_t)b*OUT_ + c] = acc + bhp[c];
    }
}

__global__ __launch_bounds__(256)
void head_smax(const float* __restrict__ logits, float* __restrict__ out){
    __shared__ float red[8];
    const int b = blockIdx.x, t = threadIdx.x;
    float acc[4];
    #pragma unroll
    for (int j=0;j<4;j++){
        int c = t + j*256;
        acc[j] = (c < OUT_) ? logits[(size_t)b*OUT_ + c] : -1e30f;
    }
    float mx = fmaxf(fmaxf(acc[0],acc[1]), fmaxf(acc[2],acc[3]));
    #pragma unroll
    for (int off=32; off>0; off>>=1) mx = fmaxf(mx, __shfl_xor(mx, off, 64));
    if ((t & 63) == 0) red[t>>6] = mx;
    __syncthreads();
    mx = fmaxf(fmaxf(red[0],red[1]), fmaxf(red[2],red[3]));
    float e[4]; float ss = 0.f;
    #pragma unroll
    for (int j=0;j<4;j++){
        int c = t + j*256;
        if (c < OUT_){ e[j] = expf(acc[j]-mx); ss += e[j]; } else e[j] = 0.f;
    }
    #pragma unroll
    for (int off=32; off>0; off>>=1) ss += __shfl_xor(ss, off, 64);
    if ((t & 63) == 0) red[4 + (t>>6)] = ss;
    __syncthreads();
    ss = red[4]+red[5]+red[6]+red[7];
    float inv = 1.f/ss;
    #pragma unroll
    for (int j=0;j<4;j++){
        int c = t + j*256;
        if (c < OUT_) out[(size_t)b*OUT_ + c] = e[j]*inv;
    }
}

extern "C" void kernel_launch(void* const* d_in, const int* in_sizes, int n_in,
                              void* d_out, int out_size, void* d_ws, size_t ws_size,
                              hipStream_t stream){
    const float* images = (const float*)d_in[0];
    const float* W_map  = (const float*)d_in[1];
    const float* b_map  = (const float*)d_in[2];
    const float* cls    = (const float*)d_in[3];
    const float* pos    = (const float*)d_in[4];
    const float* ln1s   = (const float*)d_in[5];
    const float* ln1b   = (const float*)d_in[6];
    const float* Wq     = (const float*)d_in[7];
    const float* bq     = (const float*)d_in[8];
    const float* Wk     = (const float*)d_in[9];
    const float* bk     = (const float*)d_in[10];
    const float* Wv     = (const float*)d_in[11];
    const float* bv     = (const float*)d_in[12];
    const float* ln2s   = (const float*)d_in[13];
    const float* ln2b   = (const float*)d_in[14];
    const float* W1     = (const float*)d_in[15];
    const float* b1     = (const float*)d_in[16];
    const float* W2     = (const float*)d_in[17];
    const float* b2     = (const float*)d_in[18];
    const float* Wh     = (const float*)d_in[19];
    const float* bh     = (const float*)d_in[20];
    float* out = (float*)d_out;

    // workspace (floats):
    // [x: BSD_][R: 4*BSD_ -- holds qb/kb/vt(bf16)+h during attn phase; m during MLP]
    // [hbf: BSD_/2][wt1: 2.36M][wt2: 2.36M]; logits reuses hbf region at head time
    const size_t QKV_ELEMS = (size_t)B_*NH_*SP_*DH_;   // 5,505,024 u16 = 2,752,512 floats
    float* ws = (float*)d_ws;
    float* x   = ws;
    float* R   = ws + BSD_;
    u16*   qb  = (u16*)R;
    u16*   kb  = qb + QKV_ELEMS;
    u16*   vt  = kb + QKV_ELEMS;
    float* h   = R + 3*(QKV_ELEMS/2);
    float* m   = R;
    u16*   hbf = (u16*)(ws + 5*BSD_);
    u16*   wt1 = hbf + BSD_;
    u16*   wt2 = wt1 + (size_t)L_*D_*MLPD_;
    float* logits = (float*)hbf;   // dead region by head time

    wt_cvt<<<dim3(MLPD_/32, D_/32, L_), dim3(32,8), 0, stream>>>(W1, wt1, D_, MLPD_);
    wt_cvt<<<dim3(D_/32, MLPD_/32, L_), dim3(32,8), 0, stream>>>(W2, wt2, MLPD_, D_);

    vit_cls<<<dim3(96), dim3(256), 0, stream>>>(cls, pos, x);
    vit_patch<<<dim3(98,3), dim3(256), 0, stream>>>(images, W_map, b_map, pos, x);

    for (int l=0; l<L_; l++){
        vit_ln<0><<<dim3(BS_/4), dim3(256), 0, stream>>>(x, ln1s + l*D_, ln1b + l*D_, (void*)h);
        vit_qkv<<<dim3(197,18), dim3(256), 0, stream>>>(h,
            Wq + (size_t)l*NH_*DH_*DH_, Wk + (size_t)l*NH_*DH_*DH_, Wv + (size_t)l*NH_*DH_*DH_,
            bq + (size_t)l*NH_*DH_,     bk + (size_t)l*NH_*DH_,     bv + (size_t)l*NH_*DH_,
            qb, kb, vt);
        vit_attn_mfma<<<dim3(B_*NH_, 4), dim3(256), 0, stream>>>(qb, kb, vt, x);
        vit_ln<1><<<dim3(BS_/4), dim3(256), 0, stream>>>(x, ln2s + l*D_, ln2b + l*D_, (void*)hbf);
        vit_gemm_mfma<1,0><<<dim3(99,12), dim3(256), 0, stream>>>(
            (const void*)hbf, wt1 + (size_t)l*D_*MLPD_, b1 + (size_t)l*MLPD_, m, BS_, MLPD_, D_);
        vit_gemm_mfma<0,1><<<dim3(99,3), dim3(256), 0, stream>>>(
            (const void*)m, wt2 + (size_t)l*MLPD_*D_, b2 + (size_t)l*D_, x, BS_, D_, MLPD_);
    }
    head_logits<<<dim3(4, B_), dim3(256), 0, stream>>>(x, Wh, bh, logits);
    head_smax<<<dim3(B_), dim3(256), 0, stream>>>(logits, out);
}